// Round 4
// baseline (281.425 us; speedup 1.0000x reference)
//
#include <hip/hip_runtime.h>

#define MTOT 65536   // B*V
#define KTOT 1024    // F
#define NTOT 1024    // U

#define BM 256
#define BN 256
#define BK 64
#define NTILE (KTOT / BK)   // 16

typedef __attribute__((ext_vector_type(4))) unsigned int u32x4;
typedef __attribute__((ext_vector_type(4))) float f32x4;
typedef __attribute__((ext_vector_type(8))) __bf16 bf16x8;
typedef __attribute__((ext_vector_type(4))) unsigned short u16x4;

static __device__ __forceinline__ unsigned short f2bf(float f) {
    unsigned int u = __float_as_uint(f);
    u += 0x7fffu + ((u >> 16) & 1u);   // round-to-nearest-even
    return (unsigned short)(u >> 16);
}

#define GLOAD16(g, l)                                                              \
    __builtin_amdgcn_global_load_lds(                                              \
        (const __attribute__((address_space(1))) void*)(g),                        \
        (__attribute__((address_space(3))) void*)(l), 16, 0, 0)

#define VMCNT(n) asm volatile("s_waitcnt vmcnt(" #n ")" ::: "memory")
#define LGKM0    asm volatile("s_waitcnt lgkmcnt(0)" ::: "memory")
#define CFENCE   asm volatile("" ::: "memory")
#define SBAR     __builtin_amdgcn_sched_barrier(0)
#define BAR()    __builtin_amdgcn_s_barrier()

// ---- prep: valid + fp32->bf16 feature convert + invalid-row passthrough ----
__global__ __launch_bounds__(256) void prep_kernel(const int* __restrict__ adj,
                                                   const float* __restrict__ feat,
                                                   unsigned short* __restrict__ abf,
                                                   unsigned char* __restrict__ valid,
                                                   float* __restrict__ out) {
    const int row  = blockIdx.x * 4 + (threadIdx.x >> 6);
    const int lane = threadIdx.x & 63;
    const int2 a2  = reinterpret_cast<const int2*>(adj)[(size_t)row * 64 + lane];
    const bool anyv = __any((a2.x >= 0) || (a2.y >= 0)) != 0;

    const f32x4* frow = reinterpret_cast<const f32x4*>(feat + (size_t)row * KTOT);
    u16x4*       brow = reinterpret_cast<u16x4*>(abf + (size_t)row * KTOT);
    f32x4*       orow = reinterpret_cast<f32x4*>(out + (size_t)row * NTOT);
    if (anyv) {
#pragma unroll
        for (int i = 0; i < 4; ++i) {
            const f32x4 v = frow[lane + 64 * i];
            u16x4 b;
            b.x = f2bf(v[0]); b.y = f2bf(v[1]); b.z = f2bf(v[2]); b.w = f2bf(v[3]);
            brow[lane + 64 * i] = b;
        }
    } else {
#pragma unroll
        for (int i = 0; i < 4; ++i)
            orow[lane + 64 * i] = frow[lane + 64 * i];   // K==N passthrough
    }
    if (lane == 0) valid[row] = anyv ? 1 : 0;
}

// ---- prep 2: kT[n][k] = bf16(kern[k][n]) ----
__global__ __launch_bounds__(256) void transposeB_kernel(const float* __restrict__ kern,
                                                         unsigned short* __restrict__ kT) {
    __shared__ float tile[32][33];
    const int bx = blockIdx.x & 31;
    const int by = blockIdx.x >> 5;
    const int tx = threadIdx.x & 31;
    const int ty = threadIdx.x >> 5;
#pragma unroll
    for (int r = 0; r < 4; ++r)
        tile[ty + r * 8][tx] = kern[(size_t)(by * 32 + ty + r * 8) * NTOT + bx * 32 + tx];
    __syncthreads();
#pragma unroll
    for (int r = 0; r < 4; ++r)
        kT[(size_t)(bx * 32 + ty + r * 8) * KTOT + by * 32 + tx] = f2bf(tile[tx][ty + r * 8]);
}

// ---- main GEMM: 256x256, BK=64, 8-phase-style schedule, counted vmcnt ----
// A bf16 [M][K], Bt bf16 [N][K]. 512 threads = 8 waves (2M x 4N), 128 KiB LDS.
__global__ __launch_bounds__(512, 2) void gemm_kernel(const unsigned short* __restrict__ A,
                                                      const unsigned short* __restrict__ Bt,
                                                      const float* __restrict__ bias,
                                                      const unsigned char* __restrict__ valid,
                                                      float* __restrict__ out) {
    // [2 dbuf][2 half][128 rows][64 cols] ushort, swizzled 16B chunks (phys = log ^ (row&7))
    __shared__ __align__(16) unsigned short Asm[32768];
    __shared__ __align__(16) unsigned short Bsm[32768];

    const int tid  = threadIdx.x;
    const int lane = tid & 63;
    const int wv   = tid >> 6;     // 0..7
    const int wm   = wv >> 2;      // wave M half (rows wm*128..+128)
    const int wn   = wv & 3;       // wave N quarter (cols wn*64..+64)

    // bijective XCD swizzle (nwg = 1024, divisible by 8)
    const int cpx = (int)gridDim.x >> 3;
    const int swz = ((int)blockIdx.x & 7) * cpx + ((int)blockIdx.x >> 3);
    const int bm  = swz >> 2;      // 0..255
    const int bn  = swz & 3;       // 0..3
    const size_t m0 = (size_t)bm * BM;
    const int    n0 = bn * BN;

    // staging lane constants: thread covers rows {wv*8+(lane>>3), +64}, phys chunk lane&7
    const int s_goff = (wv * 8 + (lane >> 3)) * KTOT + (((lane & 7) ^ ((lane >> 3) & 7)) << 3);
    const int s_loff = wv << 9;    // wave-uniform, ushort units (lane*16B auto-appended)

    const unsigned short* Agl = A  + m0 * (size_t)KTOT;
    const unsigned short* Bgl = Bt + (size_t)n0 * KTOT;

#define STAGE_A(d, h, kt) do {                                                      \
        const unsigned short* _s = Agl + (size_t)((h) * 128) * KTOT + (kt) * 64 + s_goff; \
        unsigned short* _l = &Asm[(d) * 16384 + (h) * 8192 + s_loff];               \
        GLOAD16(_s, _l);                                                            \
        GLOAD16(_s + (size_t)64 * KTOT, _l + 4096);                                 \
    } while (0)
#define STAGE_B(d, h, kt) do {                                                      \
        const unsigned short* _s = Bgl + (size_t)((h) * 128) * KTOT + (kt) * 64 + s_goff; \
        unsigned short* _l = &Bsm[(d) * 16384 + (h) * 8192 + s_loff];               \
        GLOAD16(_s, _l);                                                            \
        GLOAD16(_s + (size_t)64 * KTOT, _l + 4096);                                 \
    } while (0)

    // fragment read addressing
    const int lr = lane & 15;
    const int g4 = lane >> 4;
    const int chunk = (g4 ^ (lr & 7)) << 3;          // phys 16B chunk (kh flips via ^32)
    const int abase = wm * 8192 + lr * 64 + chunk;
    const int bbase = (wn >> 1) * 8192 + (wn & 1) * 4096 + lr * 64 + chunk;

#define AFR(d, m, kh) __builtin_bit_cast(bf16x8, \
        *reinterpret_cast<const u32x4*>(&Asm[(d) * 16384 + (m) * 1024 + (abase ^ ((kh) * 32))]))
#define BFR(d, n, kh) __builtin_bit_cast(bf16x8, \
        *reinterpret_cast<const u32x4*>(&Bsm[(d) * 16384 + (n) * 1024 + (bbase ^ ((kh) * 32))]))

#define RDA(d, F, mb) do {                                                          \
        F[0][0] = AFR(d, (mb), 0);     F[0][1] = AFR(d, (mb), 1);                   \
        F[1][0] = AFR(d, (mb) + 1, 0); F[1][1] = AFR(d, (mb) + 1, 1);               \
    } while (0)
#define RDB(d, BB) do {                                                             \
        _Pragma("unroll") for (int _n = 0; _n < 4; ++_n) {                          \
            BB[_n][0] = BFR(d, _n, 0); BB[_n][1] = BFR(d, _n, 1); }                 \
    } while (0)

    f32x4 acc[8][4];
#pragma unroll
    for (int m = 0; m < 8; ++m)
#pragma unroll
        for (int n = 0; n < 4; ++n)
            acc[m][n] = {0.0f, 0.0f, 0.0f, 0.0f};

#define MFMA_PH(M0, F, BB) do {                                                     \
        __builtin_amdgcn_s_setprio(1);                                              \
        _Pragma("unroll") for (int _kh = 0; _kh < 2; ++_kh)                         \
        _Pragma("unroll") for (int _i = 0; _i < 2; ++_i)                            \
        _Pragma("unroll") for (int _n = 0; _n < 4; ++_n)                            \
            acc[(M0) + _i][_n] = __builtin_amdgcn_mfma_f32_16x16x32_bf16(           \
                F[_i][_kh], BB[_n][_kh], acc[(M0) + _i][_n], 0, 0, 0);              \
        __builtin_amdgcn_s_setprio(0);                                              \
    } while (0)

    bf16x8 aX[2][2], aY[2][2], Bc[4][2], Bn[4][2];

    // prologue: tile0 (A+B) + tile1 (B) in flight; confirm tile0, leave B(1)
    STAGE_A(0, 0, 0); STAGE_A(0, 1, 0); STAGE_B(0, 0, 0); STAGE_B(0, 1, 0);
    STAGE_B(1, 0, 1); STAGE_B(1, 1, 1);
    VMCNT(4);
    BAR(); CFENCE;
    RDB(0, Bc);
    RDA(0, aX, 0);

    // group G consumes tile G (dbuf d=G&1): A-units of G+1 -> dbuf dn (ph0,1);
    // B-units of G+2 -> dbuf d (ph2,3); vmcnt(4) at ph3 confirms tile G+1 fully,
    // leaving B(G+2)'s 4 loads in flight. Phase-start lgkmcnt(0)+barrier = WAR proof.
#define GROUP(d, dn, Bcur, Bnxt, G) do {                                            \
        const bool _hasA = (G) < NTILE - 1, _hasB = (G) < NTILE - 2;                \
        /* phase 0 */                                                               \
        LGKM0; SBAR; BAR(); CFENCE;                                                 \
        if (_hasA) STAGE_A(dn, 0, (G) + 1);                                         \
        RDA(d, aY, 2);                                                              \
        MFMA_PH(0, aX, Bcur);                                                       \
        /* phase 1 */                                                               \
        LGKM0; SBAR; BAR(); CFENCE;                                                 \
        if (_hasA) STAGE_A(dn, 1, (G) + 1);                                         \
        RDA(d, aX, 4);                                                              \
        MFMA_PH(2, aY, Bcur);                                                       \
        /* phase 2 */                                                               \
        LGKM0; SBAR; BAR(); CFENCE;                                                 \
        if (_hasB) STAGE_B(d, 0, (G) + 2);                                          \
        RDA(d, aY, 6);                                                              \
        MFMA_PH(4, aX, Bcur);                                                       \
        /* phase 3 */                                                               \
        LGKM0; SBAR;                                                                \
        if (_hasB) STAGE_B(d, 1, (G) + 2);                                          \
        if ((G) < NTILE - 2)       VMCNT(4);                                        \
        else if ((G) == NTILE - 2) VMCNT(0);                                        \
        BAR(); CFENCE;                                                              \
        if (_hasA) { RDB(dn, Bnxt); RDA(dn, aX, 0); }                               \
        MFMA_PH(6, aY, Bcur);                                                       \
    } while (0)

    for (int G = 0; G < NTILE; G += 2) {
        GROUP(0, 1, Bc, Bn, G);
        GROUP(1, 0, Bn, Bc, G + 1);
    }

    // epilogue: C/D layout col=lane&15, row=(lane>>4)*4+q ; store valid rows only
    float bv[4];
#pragma unroll
    for (int n = 0; n < 4; ++n)
        bv[n] = bias[n0 + wn * 64 + n * 16 + lr];

#pragma unroll
    for (int m = 0; m < 8; ++m) {
#pragma unroll
        for (int q = 0; q < 4; ++q) {
            const size_t row = m0 + wm * 128 + m * 16 + g4 * 4 + q;
            if (valid[row]) {
                const size_t ro = row * NTOT + n0 + wn * 64 + lr;
#pragma unroll
                for (int n = 0; n < 4; ++n)
                    out[ro + n * 16] = fmaxf(acc[m][n][q] + bv[n], 0.0f);
            }
        }
    }
#undef STAGE_A
#undef STAGE_B
#undef AFR
#undef BFR
#undef RDA
#undef RDB
#undef MFMA_PH
#undef GROUP
}

// ================= fallback path (ws too small; fp32-A reg-staging) =================
#define FBM 128
#define FBN 128
#define FBK 32

__global__ __launch_bounds__(256) void valid_kernel(const int* __restrict__ adj,
                                                    unsigned char* __restrict__ valid) {
    const int row  = blockIdx.x * 4 + (threadIdx.x >> 6);
    const int lane = threadIdx.x & 63;
    const int2 v = reinterpret_cast<const int2*>(adj)[(size_t)row * 64 + lane];
    const int anyv = __any((v.x >= 0) || (v.y >= 0));
    if (lane == 0) valid[row] = anyv ? 1 : 0;
}

__global__ __launch_bounds__(256) void gemm_fb(const float* __restrict__ A,
                                               const unsigned short* __restrict__ Bt,
                                               const float* __restrict__ bias,
                                               const unsigned char* __restrict__ valid,
                                               float* __restrict__ out) {
    __shared__ __align__(16) unsigned short Asm[2][FBM * FBK];
    __shared__ __align__(16) unsigned short Bsm[2][FBN * FBK];
    const int tid = threadIdx.x;
    const int bm = blockIdx.x >> 3;
    const int bn = blockIdx.x & 7;
    const size_t m0 = (size_t)bm * FBM;
    const int n0 = bn * FBN;
    const int ja = tid & 7, ra0 = tid >> 3;
    const int jb = tid & 3, rb0 = tid >> 2;
    const int wv = tid >> 6, wr = wv >> 1, wc = wv & 1;
    const int lane = tid & 63, lr = lane & 15, g = lane >> 4;
    f32x4 acc[4][4];
#pragma unroll
    for (int m = 0; m < 4; ++m)
#pragma unroll
        for (int n = 0; n < 4; ++n) acc[m][n] = {0.f, 0.f, 0.f, 0.f};
    int awidx[4], bwidx[2], aridx[4], bridx[4];
#pragma unroll
    for (int t = 0; t < 4; ++t) {
        const int row = ra0 + t * 32;
        awidx[t] = row * 32 + (((ja >> 1) ^ ((row >> 1) & 3)) * 8) + (ja & 1) * 4;
    }
#pragma unroll
    for (int t = 0; t < 2; ++t) {
        const int row = rb0 + t * 64;
        bwidx[t] = row * 32 + ((jb ^ ((row >> 1) & 3)) * 8);
    }
#pragma unroll
    for (int m = 0; m < 4; ++m) {
        const int row = wr * 64 + m * 16 + lr;
        aridx[m] = row * 32 + ((g ^ ((row >> 1) & 3)) * 8);
    }
#pragma unroll
    for (int n = 0; n < 4; ++n) {
        const int row = wc * 64 + n * 16 + lr;
        bridx[n] = row * 32 + ((g ^ ((row >> 1) & 3)) * 8);
    }
    const int NT = KTOT / FBK;
    f32x4 areg[4];
    u32x4 breg[2];
#pragma unroll
    for (int t = 0; t < 4; ++t)
        areg[t] = reinterpret_cast<const f32x4*>(A + (m0 + ra0 + t * 32) * KTOT)[ja];
#pragma unroll
    for (int t = 0; t < 2; ++t)
        breg[t] = reinterpret_cast<const u32x4*>(Bt + (size_t)(n0 + rb0 + t * 64) * KTOT)[jb];
#pragma unroll
    for (int t = 0; t < 4; ++t) {
        unsigned long long w = (unsigned long long)f2bf(areg[t][0]) |
                               ((unsigned long long)f2bf(areg[t][1]) << 16) |
                               ((unsigned long long)f2bf(areg[t][2]) << 32) |
                               ((unsigned long long)f2bf(areg[t][3]) << 48);
        *reinterpret_cast<unsigned long long*>(&Asm[0][awidx[t]]) = w;
    }
#pragma unroll
    for (int t = 0; t < 2; ++t) *reinterpret_cast<u32x4*>(&Bsm[0][bwidx[t]]) = breg[t];
    int cur = 0;
    for (int kt = 0; kt < NT; ++kt) {
        const bool more = (kt + 1) < NT;
        if (more) {
            const int koff = (kt + 1) * FBK;
#pragma unroll
            for (int t = 0; t < 4; ++t)
                areg[t] = reinterpret_cast<const f32x4*>(A + (m0 + ra0 + t * 32) * KTOT + koff)[ja];
#pragma unroll
            for (int t = 0; t < 2; ++t)
                breg[t] = reinterpret_cast<const u32x4*>(Bt + (size_t)(n0 + rb0 + t * 64) * KTOT + koff)[jb];
        }
        __syncthreads();
        bf16x8 af[4], bfr[4];
#pragma unroll
        for (int m = 0; m < 4; ++m)
            af[m] = __builtin_bit_cast(bf16x8, *reinterpret_cast<const u32x4*>(&Asm[cur][aridx[m]]));
#pragma unroll
        for (int n = 0; n < 4; ++n)
            bfr[n] = __builtin_bit_cast(bf16x8, *reinterpret_cast<const u32x4*>(&Bsm[cur][bridx[n]]));
#pragma unroll
        for (int m = 0; m < 4; ++m)
#pragma unroll
            for (int n = 0; n < 4; ++n)
                acc[m][n] = __builtin_amdgcn_mfma_f32_16x16x32_bf16(af[m], bfr[n], acc[m][n], 0, 0, 0);
        if (more) {
            const int nxt = cur ^ 1;
#pragma unroll
            for (int t = 0; t < 4; ++t) {
                unsigned long long w = (unsigned long long)f2bf(areg[t][0]) |
                                       ((unsigned long long)f2bf(areg[t][1]) << 16) |
                                       ((unsigned long long)f2bf(areg[t][2]) << 32) |
                                       ((unsigned long long)f2bf(areg[t][3]) << 48);
                *reinterpret_cast<unsigned long long*>(&Asm[nxt][awidx[t]]) = w;
            }
#pragma unroll
            for (int t = 0; t < 2; ++t) *reinterpret_cast<u32x4*>(&Bsm[nxt][bwidx[t]]) = breg[t];
        }
        cur ^= 1;
    }
    float bv[4];
#pragma unroll
    for (int n = 0; n < 4; ++n) bv[n] = bias[n0 + wc * 64 + n * 16 + lr];
#pragma unroll
    for (int m = 0; m < 4; ++m) {
#pragma unroll
        for (int q = 0; q < 4; ++q) {
            const size_t row = m0 + wr * 64 + m * 16 + g * 4 + q;
            const bool v = valid[row] != 0;
            const size_t ro = row * (size_t)NTOT;
#pragma unroll
            for (int n = 0; n < 4; ++n) {
                const int col = n0 + wc * 64 + n * 16 + lr;
                out[ro + col] = v ? fmaxf(acc[m][n][q] + bv[n], 0.0f) : A[ro + col];
            }
        }
    }
}

extern "C" void kernel_launch(void* const* d_in, const int* in_sizes, int n_in,
                              void* d_out, int out_size, void* d_ws, size_t ws_size,
                              hipStream_t stream) {
    const int*   adj  = (const int*)d_in[0];
    const float* feat = (const float*)d_in[1];
    const float* kern = (const float*)d_in[2];
    const float* bias = (const float*)d_in[3];
    float* out = (float*)d_out;

    unsigned short* kT    = (unsigned short*)d_ws;                             // 2 MB
    unsigned char*  valid = (unsigned char*)d_ws + 2 * 1024 * 1024;            // 64 KB
    unsigned short* abf   = (unsigned short*)((char*)d_ws + 2 * 1024 * 1024 + 65536);

    const size_t need = 2ull * 1024 * 1024 + 65536 + (size_t)MTOT * KTOT * 2;

    transposeB_kernel<<<(KTOT / 32) * (NTOT / 32), 256, 0, stream>>>(kern, kT);
    if (ws_size >= need) {
        prep_kernel<<<MTOT / 4, 256, 0, stream>>>(adj, feat, abf, valid, out);
        gemm_kernel<<<(MTOT / BM) * (NTOT / BN), 512, 0, stream>>>(abf, kT, bias, valid, out);
    } else {
        valid_kernel<<<MTOT / 4, 256, 0, stream>>>(adj, valid);
        gemm_fb<<<(MTOT / FBM) * (NTOT / FBN), 256, 0, stream>>>(feat, kT, bias, valid, out);
    }
}

// Round 5
// 259.433 us; speedup vs baseline: 1.0848x; 1.0848x over previous
//
#include <hip/hip_runtime.h>

#define MTOT 65536   // B*V
#define KTOT 1024    // F
#define NTOT 1024    // U

#define BM 256
#define BN 256
#define BK 64
#define NTILE (KTOT / BK)   // 16

typedef __attribute__((ext_vector_type(4))) unsigned int u32x4;
typedef __attribute__((ext_vector_type(4))) float f32x4;
typedef __attribute__((ext_vector_type(8))) __bf16 bf16x8;
typedef __attribute__((ext_vector_type(4))) unsigned short u16x4;

static __device__ __forceinline__ unsigned short f2bf(float f) {
    unsigned int u = __float_as_uint(f);
    u += 0x7fffu + ((u >> 16) & 1u);   // round-to-nearest-even
    return (unsigned short)(u >> 16);
}

#define GLOAD16(g, l)                                                              \
    __builtin_amdgcn_global_load_lds(                                              \
        (const __attribute__((address_space(1))) void*)(g),                        \
        (__attribute__((address_space(3))) void*)(l), 16, 0, 0)

#define VMCNT(n) asm volatile("s_waitcnt vmcnt(" #n ")" ::: "memory")
#define LGKM0    asm volatile("s_waitcnt lgkmcnt(0)" ::: "memory")
#define CFENCE   asm volatile("" ::: "memory")
#define SBAR     __builtin_amdgcn_sched_barrier(0)
#define BAR()    __builtin_amdgcn_s_barrier()

// ---- prep: valid + fp32->bf16 feature convert + invalid-row passthrough ----
__global__ __launch_bounds__(256) void prep_kernel(const int* __restrict__ adj,
                                                   const float* __restrict__ feat,
                                                   unsigned short* __restrict__ abf,
                                                   unsigned char* __restrict__ valid,
                                                   float* __restrict__ out) {
    const int row  = blockIdx.x * 4 + (threadIdx.x >> 6);
    const int lane = threadIdx.x & 63;
    const int2 a2  = reinterpret_cast<const int2*>(adj)[(size_t)row * 64 + lane];
    const bool anyv = __any((a2.x >= 0) || (a2.y >= 0)) != 0;

    const f32x4* frow = reinterpret_cast<const f32x4*>(feat + (size_t)row * KTOT);
    u16x4*       brow = reinterpret_cast<u16x4*>(abf + (size_t)row * KTOT);
    f32x4*       orow = reinterpret_cast<f32x4*>(out + (size_t)row * NTOT);
    if (anyv) {
#pragma unroll
        for (int i = 0; i < 4; ++i) {
            const f32x4 v = frow[lane + 64 * i];
            u16x4 b;
            b.x = f2bf(v[0]); b.y = f2bf(v[1]); b.z = f2bf(v[2]); b.w = f2bf(v[3]);
            brow[lane + 64 * i] = b;
        }
    } else {
#pragma unroll
        for (int i = 0; i < 4; ++i)
            orow[lane + 64 * i] = frow[lane + 64 * i];   // K==N passthrough
    }
    if (lane == 0) valid[row] = anyv ? 1 : 0;
}

// ---- prep 2: kT[n][k] = bf16(kern[k][n]) ----
__global__ __launch_bounds__(256) void transposeB_kernel(const float* __restrict__ kern,
                                                         unsigned short* __restrict__ kT) {
    __shared__ float tile[32][33];
    const int bx = blockIdx.x & 31;
    const int by = blockIdx.x >> 5;
    const int tx = threadIdx.x & 31;
    const int ty = threadIdx.x >> 5;
#pragma unroll
    for (int r = 0; r < 4; ++r)
        tile[ty + r * 8][tx] = kern[(size_t)(by * 32 + ty + r * 8) * NTOT + bx * 32 + tx];
    __syncthreads();
#pragma unroll
    for (int r = 0; r < 4; ++r)
        kT[(size_t)(bx * 32 + ty + r * 8) * KTOT + by * 32 + tx] = f2bf(tile[tx][ty + r * 8]);
}

// ---- main GEMM: 256x256, BK=64, faithful 8-phase template, counted vmcnt ----
// A bf16 [M][K], Bt bf16 [N][K]. 512 threads = 8 waves (2M x 4N), 128 KiB LDS.
// d0 = even K-tiles, d1 = odd K-tiles (static). Per iteration (2 tiles, 8 phases):
//   phase = { ds_read this phase's frags; stage 1 half-tile; BAR; lgkm0+SBAR;
//             setprio(1); 16 MFMA (quadrant); setprio(0); [vmcnt ph4/ph8]; BAR }
// Staging rotation (WAR-safe by the phase that confirmed the region's reads):
//   ph1 A(2i+1)h0  ph2 A(2i+1)h1   [d1.A free after prev ph8 lgkm0+BAR]
//   ph3 B(2i+2)h0  ph4 B(2i+2)h1   [d0.B free after ph1]
//   ph5 A(2i+2)h0  ph6 A(2i+2)h1   [d0.A free after ph4]
//   ph7 B(2i+3)h0  ph8 B(2i+3)h1   [d1.B free after ph5]
// vmcnt(4) at ph4 confirms A(2i+1)+B(2i+1) (tile read at ph5); at ph8 confirms
// A(2i+2)+B(2i+2) (tile read next ph1); 2 half-tiles (4 loads) always in flight.
__global__ __launch_bounds__(512, 2) void gemm_kernel(const unsigned short* __restrict__ A,
                                                      const unsigned short* __restrict__ Bt,
                                                      const float* __restrict__ bias,
                                                      const unsigned char* __restrict__ valid,
                                                      float* __restrict__ out) {
    // [2 d][2 half][128 rows][64 cols] ushort, swizzled 16B chunks (phys = log ^ (row&7))
    __shared__ __align__(16) unsigned short Asm[32768];
    __shared__ __align__(16) unsigned short Bsm[32768];

    const int tid  = threadIdx.x;
    const int lane = tid & 63;
    const int wv   = tid >> 6;     // 0..7
    const int wm   = wv >> 2;      // wave M half (rows wm*128..+128)
    const int wn   = wv & 3;       // wave N quarter (cols wn*64..+64)

    // bijective XCD swizzle (nwg = 1024, divisible by 8)
    const int cpx = (int)gridDim.x >> 3;
    const int swz = ((int)blockIdx.x & 7) * cpx + ((int)blockIdx.x >> 3);
    const int bm  = swz >> 2;      // 0..255
    const int bn  = swz & 3;       // 0..3
    const size_t m0 = (size_t)bm * BM;
    const int    n0 = bn * BN;

    // staging lane constants: thread covers row wv*8+(lane>>3) (+64 in 2nd gload),
    // phys chunk lane&7 -> logical (source) chunk = phys ^ (row&7)
    const int s_goff = (wv * 8 + (lane >> 3)) * KTOT + (((lane & 7) ^ ((lane >> 3) & 7)) << 3);
    const int s_loff = wv << 9;    // wave-uniform LDS base, ushort units

    const unsigned short* Agl = A  + m0 * (size_t)KTOT;
    const unsigned short* Bgl = Bt + (size_t)n0 * KTOT;

#define STAGE_A(d, h, kt) do {                                                      \
        const unsigned short* _s = Agl + (size_t)((h) * 128) * KTOT + (kt) * 64 + s_goff; \
        unsigned short* _l = &Asm[(d) * 16384 + (h) * 8192 + s_loff];               \
        GLOAD16(_s, _l);                                                            \
        GLOAD16(_s + (size_t)64 * KTOT, _l + 4096);                                 \
    } while (0)
#define STAGE_B(d, h, kt) do {                                                      \
        const unsigned short* _s = Bgl + (size_t)((h) * 128) * KTOT + (kt) * 64 + s_goff; \
        unsigned short* _l = &Bsm[(d) * 16384 + (h) * 8192 + s_loff];               \
        GLOAD16(_s, _l);                                                            \
        GLOAD16(_s + (size_t)64 * KTOT, _l + 4096);                                 \
    } while (0)

    // fragment read addressing
    const int lr = lane & 15;
    const int g4 = lane >> 4;
    const int chunk = (g4 ^ (lr & 7)) << 3;          // phys 16B chunk (kh flips via ^32)
    const int abase = wm * 8192 + lr * 64 + chunk;
    const int bbase = (wn >> 1) * 8192 + (wn & 1) * 4096 + lr * 64 + chunk;

#define AFR(d, m, kh) __builtin_bit_cast(bf16x8, \
        *reinterpret_cast<const u32x4*>(&Asm[(d) * 16384 + (m) * 1024 + (abase ^ ((kh) * 32))]))
#define BFR(d, n, kh) __builtin_bit_cast(bf16x8, \
        *reinterpret_cast<const u32x4*>(&Bsm[(d) * 16384 + (n) * 1024 + (bbase ^ ((kh) * 32))]))

#define RDA(d, mb) do {                                                             \
        aX[0][0] = AFR(d, (mb), 0);     aX[0][1] = AFR(d, (mb), 1);                 \
        aX[1][0] = AFR(d, (mb) + 1, 0); aX[1][1] = AFR(d, (mb) + 1, 1);             \
    } while (0)
#define RDB(d) do {                                                                 \
        _Pragma("unroll") for (int _n = 0; _n < 4; ++_n) {                          \
            Bc[_n][0] = BFR(d, _n, 0); Bc[_n][1] = BFR(d, _n, 1); }                 \
    } while (0)

    f32x4 acc[8][4];
#pragma unroll
    for (int m = 0; m < 8; ++m)
#pragma unroll
        for (int n = 0; n < 4; ++n)
            acc[m][n] = {0.0f, 0.0f, 0.0f, 0.0f};

#define MFMA_PH(M0) do {                                                            \
        __builtin_amdgcn_s_setprio(1);                                              \
        _Pragma("unroll") for (int _kh = 0; _kh < 2; ++_kh)                         \
        _Pragma("unroll") for (int _i = 0; _i < 2; ++_i)                            \
        _Pragma("unroll") for (int _n = 0; _n < 4; ++_n)                            \
            acc[(M0) + _i][_n] = __builtin_amdgcn_mfma_f32_16x16x32_bf16(           \
                aX[_i][_kh], Bc[_n][_kh], acc[(M0) + _i][_n], 0, 0, 0);             \
        __builtin_amdgcn_s_setprio(0);                                              \
    } while (0)

    bf16x8 aX[2][2], Bc[4][2];

    // prologue: tile0 A+B (d0) + tile1 B (d1.B); confirm tile0, leave B(1) in flight
    STAGE_A(0, 0, 0); STAGE_A(0, 1, 0); STAGE_B(0, 0, 0); STAGE_B(0, 1, 0);
    STAGE_B(1, 0, 1); STAGE_B(1, 1, 1);
    VMCNT(4);
    BAR(); CFENCE;

    for (int i = 0; i < NTILE / 2; ++i) {
        const int t1 = 2 * i + 1, t2 = 2 * i + 2, t3 = 2 * i + 3;
        const bool s2 = t2 < NTILE, s3 = t3 < NTILE;

        // ---- ph1: tile 2i (d0), quadrant 0 ----
        RDB(0); RDA(0, 0);
        STAGE_A(1, 0, t1);
        BAR(); CFENCE; LGKM0; SBAR;
        MFMA_PH(0);
        BAR(); CFENCE;
        // ---- ph2: d0 q1 ----
        RDA(0, 2);
        STAGE_A(1, 1, t1);
        BAR(); CFENCE; LGKM0; SBAR;
        MFMA_PH(2);
        BAR(); CFENCE;
        // ---- ph3: d0 q2 ----
        RDA(0, 4);
        if (s2) STAGE_B(0, 0, t2);
        BAR(); CFENCE; LGKM0; SBAR;
        MFMA_PH(4);
        BAR(); CFENCE;
        // ---- ph4: d0 q3 + vmcnt (confirms tile t1 for ph5) ----
        RDA(0, 6);
        if (s2) STAGE_B(0, 1, t2);
        BAR(); CFENCE; LGKM0; SBAR;
        MFMA_PH(6);
        if (s2) VMCNT(4); else VMCNT(0);
        BAR(); CFENCE;
        // ---- ph5: tile 2i+1 (d1), quadrant 0 ----
        RDB(1); RDA(1, 0);
        if (s2) STAGE_A(0, 0, t2);
        BAR(); CFENCE; LGKM0; SBAR;
        MFMA_PH(0);
        BAR(); CFENCE;
        // ---- ph6: d1 q1 ----
        RDA(1, 2);
        if (s2) STAGE_A(0, 1, t2);
        BAR(); CFENCE; LGKM0; SBAR;
        MFMA_PH(2);
        BAR(); CFENCE;
        // ---- ph7: d1 q2 ----
        RDA(1, 4);
        if (s3) STAGE_B(1, 0, t3);
        BAR(); CFENCE; LGKM0; SBAR;
        MFMA_PH(4);
        BAR(); CFENCE;
        // ---- ph8: d1 q3 + vmcnt (confirms tile t2 for next ph1) ----
        RDA(1, 6);
        if (s3) STAGE_B(1, 1, t3);
        BAR(); CFENCE; LGKM0; SBAR;
        MFMA_PH(6);
        if (s3) { VMCNT(4); }
        else if (s2) { VMCNT(0); }
        BAR(); CFENCE;
    }

    // epilogue: C/D layout col=lane&15, row=(lane>>4)*4+q ; store valid rows only
    float bv[4];
#pragma unroll
    for (int n = 0; n < 4; ++n)
        bv[n] = bias[n0 + wn * 64 + n * 16 + lr];

#pragma unroll
    for (int m = 0; m < 8; ++m) {
#pragma unroll
        for (int q = 0; q < 4; ++q) {
            const size_t row = m0 + wm * 128 + m * 16 + g4 * 4 + q;
            if (valid[row]) {
                const size_t ro = row * NTOT + n0 + wn * 64 + lr;
#pragma unroll
                for (int n = 0; n < 4; ++n)
                    out[ro + n * 16] = fmaxf(acc[m][n][q] + bv[n], 0.0f);
            }
        }
    }
#undef STAGE_A
#undef STAGE_B
#undef AFR
#undef BFR
#undef RDA
#undef RDB
#undef MFMA_PH
}

// ================= fallback path (ws too small; fp32-A reg-staging) =================
#define FBM 128
#define FBN 128
#define FBK 32

__global__ __launch_bounds__(256) void valid_kernel(const int* __restrict__ adj,
                                                    unsigned char* __restrict__ valid) {
    const int row  = blockIdx.x * 4 + (threadIdx.x >> 6);
    const int lane = threadIdx.x & 63;
    const int2 v = reinterpret_cast<const int2*>(adj)[(size_t)row * 64 + lane];
    const int anyv = __any((v.x >= 0) || (v.y >= 0));
    if (lane == 0) valid[row] = anyv ? 1 : 0;
}

__global__ __launch_bounds__(256) void gemm_fb(const float* __restrict__ A,
                                               const unsigned short* __restrict__ Bt,
                                               const float* __restrict__ bias,
                                               const unsigned char* __restrict__ valid,
                                               float* __restrict__ out) {
    __shared__ __align__(16) unsigned short Asm[2][FBM * FBK];
    __shared__ __align__(16) unsigned short Bsm[2][FBN * FBK];
    const int tid = threadIdx.x;
    const int bm = blockIdx.x >> 3;
    const int bn = blockIdx.x & 7;
    const size_t m0 = (size_t)bm * FBM;
    const int n0 = bn * FBN;
    const int ja = tid & 7, ra0 = tid >> 3;
    const int jb = tid & 3, rb0 = tid >> 2;
    const int wv = tid >> 6, wr = wv >> 1, wc = wv & 1;
    const int lane = tid & 63, lr = lane & 15, g = lane >> 4;
    f32x4 acc[4][4];
#pragma unroll
    for (int m = 0; m < 4; ++m)
#pragma unroll
        for (int n = 0; n < 4; ++n) acc[m][n] = {0.f, 0.f, 0.f, 0.f};
    int awidx[4], bwidx[2], aridx[4], bridx[4];
#pragma unroll
    for (int t = 0; t < 4; ++t) {
        const int row = ra0 + t * 32;
        awidx[t] = row * 32 + (((ja >> 1) ^ ((row >> 1) & 3)) * 8) + (ja & 1) * 4;
    }
#pragma unroll
    for (int t = 0; t < 2; ++t) {
        const int row = rb0 + t * 64;
        bwidx[t] = row * 32 + ((jb ^ ((row >> 1) & 3)) * 8);
    }
#pragma unroll
    for (int m = 0; m < 4; ++m) {
        const int row = wr * 64 + m * 16 + lr;
        aridx[m] = row * 32 + ((g ^ ((row >> 1) & 3)) * 8);
    }
#pragma unroll
    for (int n = 0; n < 4; ++n) {
        const int row = wc * 64 + n * 16 + lr;
        bridx[n] = row * 32 + ((g ^ ((row >> 1) & 3)) * 8);
    }
    const int NT = KTOT / FBK;
    f32x4 areg[4];
    u32x4 breg[2];
#pragma unroll
    for (int t = 0; t < 4; ++t)
        areg[t] = reinterpret_cast<const f32x4*>(A + (m0 + ra0 + t * 32) * KTOT)[ja];
#pragma unroll
    for (int t = 0; t < 2; ++t)
        breg[t] = reinterpret_cast<const u32x4*>(Bt + (size_t)(n0 + rb0 + t * 64) * KTOT)[jb];
#pragma unroll
    for (int t = 0; t < 4; ++t) {
        unsigned long long w = (unsigned long long)f2bf(areg[t][0]) |
                               ((unsigned long long)f2bf(areg[t][1]) << 16) |
                               ((unsigned long long)f2bf(areg[t][2]) << 32) |
                               ((unsigned long long)f2bf(areg[t][3]) << 48);
        *reinterpret_cast<unsigned long long*>(&Asm[0][awidx[t]]) = w;
    }
#pragma unroll
    for (int t = 0; t < 2; ++t) *reinterpret_cast<u32x4*>(&Bsm[0][bwidx[t]]) = breg[t];
    int cur = 0;
    for (int kt = 0; kt < NT; ++kt) {
        const bool more = (kt + 1) < NT;
        if (more) {
            const int koff = (kt + 1) * FBK;
#pragma unroll
            for (int t = 0; t < 4; ++t)
                areg[t] = reinterpret_cast<const f32x4*>(A + (m0 + ra0 + t * 32) * KTOT + koff)[ja];
#pragma unroll
            for (int t = 0; t < 2; ++t)
                breg[t] = reinterpret_cast<const u32x4*>(Bt + (size_t)(n0 + rb0 + t * 64) * KTOT + koff)[jb];
        }
        __syncthreads();
        bf16x8 af[4], bfr[4];
#pragma unroll
        for (int m = 0; m < 4; ++m)
            af[m] = __builtin_bit_cast(bf16x8, *reinterpret_cast<const u32x4*>(&Asm[cur][aridx[m]]));
#pragma unroll
        for (int n = 0; n < 4; ++n)
            bfr[n] = __builtin_bit_cast(bf16x8, *reinterpret_cast<const u32x4*>(&Bsm[cur][bridx[n]]));
#pragma unroll
        for (int m = 0; m < 4; ++m)
#pragma unroll
            for (int n = 0; n < 4; ++n)
                acc[m][n] = __builtin_amdgcn_mfma_f32_16x16x32_bf16(af[m], bfr[n], acc[m][n], 0, 0, 0);
        if (more) {
            const int nxt = cur ^ 1;
#pragma unroll
            for (int t = 0; t < 4; ++t) {
                unsigned long long w = (unsigned long long)f2bf(areg[t][0]) |
                                       ((unsigned long long)f2bf(areg[t][1]) << 16) |
                                       ((unsigned long long)f2bf(areg[t][2]) << 32) |
                                       ((unsigned long long)f2bf(areg[t][3]) << 48);
                *reinterpret_cast<unsigned long long*>(&Asm[nxt][awidx[t]]) = w;
            }
#pragma unroll
            for (int t = 0; t < 2; ++t) *reinterpret_cast<u32x4*>(&Bsm[nxt][bwidx[t]]) = breg[t];
        }
        cur ^= 1;
    }
    float bv[4];
#pragma unroll
    for (int n = 0; n < 4; ++n) bv[n] = bias[n0 + wc * 64 + n * 16 + lr];
#pragma unroll
    for (int m = 0; m < 4; ++m) {
#pragma unroll
        for (int q = 0; q < 4; ++q) {
            const size_t row = m0 + wr * 64 + m * 16 + g * 4 + q;
            const bool v = valid[row] != 0;
            const size_t ro = row * (size_t)NTOT;
#pragma unroll
            for (int n = 0; n < 4; ++n) {
                const int col = n0 + wc * 64 + n * 16 + lr;
                out[ro + col] = v ? fmaxf(acc[m][n][q] + bv[n], 0.0f) : A[ro + col];
            }
        }
    }
}

extern "C" void kernel_launch(void* const* d_in, const int* in_sizes, int n_in,
                              void* d_out, int out_size, void* d_ws, size_t ws_size,
                              hipStream_t stream) {
    const int*   adj  = (const int*)d_in[0];
    const float* feat = (const float*)d_in[1];
    const float* kern = (const float*)d_in[2];
    const float* bias = (const float*)d_in[3];
    float* out = (float*)d_out;

    unsigned short* kT    = (unsigned short*)d_ws;                             // 2 MB
    unsigned char*  valid = (unsigned char*)d_ws + 2 * 1024 * 1024;            // 64 KB
    unsigned short* abf   = (unsigned short*)((char*)d_ws + 2 * 1024 * 1024 + 65536);

    const size_t need = 2ull * 1024 * 1024 + 65536 + (size_t)MTOT * KTOT * 2;

    transposeB_kernel<<<(KTOT / 32) * (NTOT / 32), 256, 0, stream>>>(kern, kT);
    if (ws_size >= need) {
        prep_kernel<<<MTOT / 4, 256, 0, stream>>>(adj, feat, abf, valid, out);
        gemm_kernel<<<(MTOT / BM) * (NTOT / BN), 512, 0, stream>>>(abf, kT, bias, valid, out);
    } else {
        valid_kernel<<<MTOT / 4, 256, 0, stream>>>(adj, valid);
        gemm_fb<<<(MTOT / FBM) * (NTOT / FBN), 256, 0, stream>>>(feat, kT, bias, valid, out);
    }
}